// Round 11
// baseline (337.776 us; speedup 1.0000x reference)
//
#include <hip/hip_runtime.h>

#define S_LEN 4096
#define NH 12
#define HD 64
#define DMODEL 768
#define BATCH 2
#define MTOT (BATCH * S_LEN) /* 8192 */

typedef __bf16 bf16x8 __attribute__((ext_vector_type(8)));
typedef __bf16 bf16x4 __attribute__((ext_vector_type(4)));
typedef float f32x4 __attribute__((ext_vector_type(4)));
typedef float f32x8 __attribute__((ext_vector_type(8)));

#define SM_SCALE_LOG2E 0.18033688f /* 0.125 * log2(e), folded into Q at GEMM1 */
#define SLAB_STRIDE 4224           /* 32x64 bf16 O (4096) + 32 f32 rowsum (128) */

__device__ __forceinline__ f32x4 f32x4_zero() {
  f32x4 z = {0.f, 0.f, 0.f, 0.f};
  return z;
}

// ---------------- prep: f32 -> bf16 (vectorized) ----------------
__global__ __launch_bounds__(256) void cvt_f32_bf16(const float* __restrict__ in,
                                                    __bf16* __restrict__ out, int n8) {
  int i = blockIdx.x * 256 + threadIdx.x;
  if (i >= n8) return;
  f32x8 a = ((const f32x8*)in)[i];
  bf16x8 o;
#pragma unroll
  for (int j = 0; j < 8; ++j) o[j] = (__bf16)a[j];
  ((bf16x8*)out)[i] = o;
}

// ---------------- prep: transpose [768][N] f32 -> [N][768] bf16 ----------------
__global__ __launch_bounds__(256) void transpose_cvt(const float* __restrict__ in,
                                                     __bf16* __restrict__ out, int N) {
  __shared__ __bf16 t[64][72];  // padded
  int kb = blockIdx.x * 64, nb = blockIdx.y * 64;
  int c = threadIdx.x & 63, r0 = threadIdx.x >> 6;
#pragma unroll
  for (int i = 0; i < 16; ++i) {
    int r = r0 * 16 + i;
    t[c][r] = (__bf16)in[(size_t)(kb + r) * N + nb + c];
  }
  __syncthreads();
#pragma unroll
  for (int i = 0; i < 16; ++i) {
    int r = r0 * 16 + i;
    out[(size_t)(nb + r) * DMODEL + kb + c] = t[r][c];
  }
}

// ---------------- shared GEMM core: C[128x128] += A[128xK] * Bt[128xK]^T ----------------
__device__ __forceinline__ void gemm128_bt(const __bf16* __restrict__ A,
                                           const __bf16* __restrict__ Bt,
                                           int m0, int n0, int K,
                                           __bf16* Alds, __bf16* Blds,
                                           f32x4 acc[4][4]) {
  const int tid = threadIdx.x;
  const int l = tid & 63, w = tid >> 6;
  const int wr = w >> 1, wc = w & 1;
  const int g = l >> 4, ln = l & 15;
  for (int k0 = 0; k0 < K; k0 += 64) {
#pragma unroll
    for (int i = 0; i < 4; ++i) {
      int chunk = tid + i * 256;
      int row = chunk >> 3, cs = chunk & 7;
      int dst = row * 64 + ((cs ^ (row & 7)) << 3);
      *(bf16x8*)(Alds + dst) = *(const bf16x8*)(A + (size_t)(m0 + row) * K + k0 + cs * 8);
      *(bf16x8*)(Blds + dst) = *(const bf16x8*)(Bt + (size_t)(n0 + row) * K + k0 + cs * 8);
    }
    __syncthreads();
#pragma unroll
    for (int kk = 0; kk < 2; ++kk) {
      bf16x8 af[4], bfr[4];
#pragma unroll
      for (int mi = 0; mi < 4; ++mi) {
        int row = wr * 64 + mi * 16 + ln;
        af[mi] = *(const bf16x8*)(Alds + row * 64 + ((((kk << 2) + g) ^ (row & 7)) << 3));
      }
#pragma unroll
      for (int ni = 0; ni < 4; ++ni) {
        int row = wc * 64 + ni * 16 + ln;
        bfr[ni] = *(const bf16x8*)(Blds + row * 64 + ((((kk << 2) + g) ^ (row & 7)) << 3));
      }
#pragma unroll
      for (int mi = 0; mi < 4; ++mi)
#pragma unroll
        for (int ni = 0; ni < 4; ++ni)
          acc[mi][ni] =
              __builtin_amdgcn_mfma_f32_16x16x32_bf16(af[mi], bfr[ni], acc[mi][ni], 0, 0, 0);
    }
    __syncthreads();
  }
}

// ---------------- GEMM1: qkv = xb @ Wqkv + bqkv; Q pre-scaled by 0.125*log2e;
// scatter Q,K [B,H,S,Hd]; V transposed [B,H,Hd,S] ----------------
__global__ __launch_bounds__(256) void gemm_qkv(const __bf16* __restrict__ xb,
                                                const __bf16* __restrict__ Wt,
                                                const float* __restrict__ bqkv,
                                                __bf16* __restrict__ Qo,
                                                __bf16* __restrict__ Ko,
                                                __bf16* __restrict__ Vto) {
  __shared__ __bf16 Alds[128 * 64];
  __shared__ __bf16 Blds[128 * 64];
  int bm = blockIdx.x & 63, bn = blockIdx.x >> 6;
  int m0 = bm * 128, n0 = bn * 128;
  f32x4 acc[4][4];
#pragma unroll
  for (int i = 0; i < 4; ++i)
#pragma unroll
    for (int j = 0; j < 4; ++j) acc[i][j] = f32x4_zero();
  gemm128_bt(xb, Wt, m0, n0, DMODEL, Alds, Blds, acc);

  const int l = threadIdx.x & 63, w = threadIdx.x >> 6;
  const int wr = w >> 1, wc = w & 1, g = l >> 4, ln = l & 15;
#pragma unroll
  for (int ni = 0; ni < 4; ++ni) {
    int ncol = n0 + wc * 64 + ni * 16 + ln;
    int which = ncol / DMODEL;  // 0=q 1=k 2=v (uniform per 16-col fragment)
    int dd = ncol - which * DMODEL;
    int h = dd >> 6, hd = dd & 63;
    float bias = bqkv[ncol];
    if (which == 2) {
#pragma unroll
      for (int mi = 0; mi < 4; ++mi)
#pragma unroll
        for (int r = 0; r < 4; ++r) {
          int mrow = m0 + wr * 64 + mi * 16 + 4 * g + r;
          int b = mrow >> 12, s = mrow & (S_LEN - 1);
          float v = acc[mi][ni][r] + bias;
          Vto[(((size_t)(b * NH + h) * HD) + hd) * S_LEN + s] = (__bf16)v;
        }
    } else {
      __bf16* op = (which == 0) ? Qo : Ko;
      const float scl = (which == 0) ? SM_SCALE_LOG2E : 1.0f;
#pragma unroll
      for (int mi = 0; mi < 4; ++mi)
#pragma unroll
        for (int r = 0; r < 4; ++r) {
          int mrow = m0 + wr * 64 + mi * 16 + 4 * g + r;
          int b = mrow >> 12, s = mrow & (S_LEN - 1);
          float v = (acc[mi][ni][r] + bias) * scl;
          op[((((size_t)b * NH + h) * S_LEN) + s) * HD + hd] = (__bf16)v;
        }
    }
  }
}

// ---------------- GEMM2: out = Yb @ Wout + bout (fp32 out) ----------------
__global__ __launch_bounds__(256) void gemm_out(const __bf16* __restrict__ yb,
                                                const __bf16* __restrict__ Wt,
                                                const float* __restrict__ bout,
                                                float* __restrict__ out) {
  __shared__ __bf16 Alds[128 * 64];
  __shared__ __bf16 Blds[128 * 64];
  int bm = blockIdx.x & 63, bn = blockIdx.x >> 6;
  int m0 = bm * 128, n0 = bn * 128;
  f32x4 acc[4][4];
#pragma unroll
  for (int i = 0; i < 4; ++i)
#pragma unroll
    for (int j = 0; j < 4; ++j) acc[i][j] = f32x4_zero();
  gemm128_bt(yb, Wt, m0, n0, DMODEL, Alds, Blds, acc);

  const int l = threadIdx.x & 63, w = threadIdx.x >> 6;
  const int wr = w >> 1, wc = w & 1, g = l >> 4, ln = l & 15;
#pragma unroll
  for (int ni = 0; ni < 4; ++ni) {
    int ncol = n0 + wc * 64 + ni * 16 + ln;
    float bias = bout[ncol];
#pragma unroll
    for (int mi = 0; mi < 4; ++mi)
#pragma unroll
      for (int r = 0; r < 4; ++r) {
        int mrow = m0 + wr * 64 + mi * 16 + 4 * g + r;
        out[(size_t)mrow * DMODEL + ncol] = acc[mi][ni][r] + bias;
      }
  }
}

// ---------------- causal flash attention v11 ----------------
// v10 decomposition (4 waves/block, 4608 units, split + combine), register
// diet to fit the 4-waves/SIMD boundary: gfx950's UNIFIED VGPR+AGPR file means
// v10's 116 VGPR + ~64 AGPR acc ~= 180 total -> 2 waves/SIMD (the measured
// 19-21% occupancy across v2/v5/v7/v10). Changes: (a) kf and vf TIME-SHARE one
// 32-reg buffer (no cross-iter prefetch; L2 latency covered by TLP once 4
// waves/SIMD are resident), (b) softmax fused per-jt (z: 16->4 regs).
// __launch_bounds__(256,2): cap = 512/(2*2) = 128 = exactly the boundary.
#define P_PITCH 136
#define P_SLAB (2 * 16 * P_PITCH) /* 4352 per wave */

__global__ __launch_bounds__(256, 2) void attn_fwd11(const __bf16* __restrict__ Q,
                                                     const __bf16* __restrict__ K,
                                                     const __bf16* __restrict__ Vt,
                                                     __bf16* __restrict__ Y,
                                                     char* __restrict__ Po) {
  __shared__ char Plds[4 * P_SLAB];  // per-wave slab

  const int tid = threadIdx.x;
  const int wv = tid >> 6, l = tid & 63;
  const int g = l >> 4, ln = l & 15;
  const int bi = blockIdx.x;
  const int xcd = bi & 7, v = bi >> 3;  // v in 0..143
  const int head = xcd * 3 + (v % 3);   // 3 heads per XCD
  const int r_ = (v / 3) * 4 + wv;      // rank 0..191, heavy-first

  int c, tstart, tend, part;
  bool split;
  if (r_ < 128) {  // split chunks c=127..64, two kv halves each
    c = 127 - (r_ >> 1);
    part = r_ & 1;
    int T = (c + 2) >> 1;  // ceil((32c+32)/64) kv tiles
    int h = (T + 1) >> 1;
    tstart = part ? h : 0;
    tend = part ? T : h;
    split = true;
  } else {  // direct chunks c=63..0
    c = 191 - r_;
    part = 0;
    tstart = 0;
    tend = (c + 2) >> 1;
    split = false;
  }
  const int q0A = 32 * c, q0B = q0A + 16;

  const size_t hb = (size_t)head * (S_LEN * HD);
  const __bf16* Qh = Q + hb;
  const __bf16* Vh = Vt + hb;  // [HD][S]

  char* slab = Plds + wv * P_SLAB;
  char* wbA = slab + ln * P_PITCH + 8 * g;   // + 32*jt
  char* rbA = slab + ln * P_PITCH + 16 * g;  // + 64*ks
  char* wbB = wbA + 16 * P_PITCH;
  char* rbB = rbA + 16 * P_PITCH;

  // rolling source pointers at tile tstart
  const __bf16* kp = K + hb + (size_t)(64 * tstart + ln) * HD + 8 * g;
  const __bf16* vp = Vh + (size_t)ln * S_LEN + 64 * tstart + 8 * g;

  bf16x8 qfA[2], qfB[2];
#pragma unroll
  for (int t = 0; t < 2; ++t) {
    qfA[t] = *(const bf16x8*)(Qh + (size_t)(q0A + ln) * HD + 32 * t + 8 * g);
    qfB[t] = *(const bf16x8*)(Qh + (size_t)(q0B + ln) * HD + 32 * t + 8 * g);
  }

  bf16x8 ones;
#pragma unroll
  for (int t = 0; t < 8; ++t) ones[t] = (__bf16)1.0f;

  f32x4 oA[4], oB[4], o5A, o5B;
#pragma unroll
  for (int nt = 0; nt < 4; ++nt) {
    oA[nt] = f32x4_zero();
    oB[nt] = f32x4_zero();
  }
  o5A = f32x4_zero();
  o5B = f32x4_zero();

  for (int t = tstart; t < tend; ++t) {
    const int kv0 = t * 64;
    const bool diag = (kv0 + 64) > q0A;

    // ---- load K tile (kv buffer, shared with V below) ----
    bf16x8 kv[4][2];
#pragma unroll
    for (int jt = 0; jt < 4; ++jt)
#pragma unroll
      for (int t2 = 0; t2 < 2; ++t2)
        kv[jt][t2] = *(const bf16x8*)(kp + 16 * jt * HD + 32 * t2);
    kp += (size_t)64 * HD;

    // ---- QK^T + fused softmax, subtile A then B (z is 4 regs) ----
    if (!diag) {
#pragma unroll
      for (int jt = 0; jt < 4; ++jt) {
        f32x4 z = f32x4_zero();
        z = __builtin_amdgcn_mfma_f32_16x16x32_bf16(kv[jt][0], qfA[0], z, 0, 0, 0);
        z = __builtin_amdgcn_mfma_f32_16x16x32_bf16(kv[jt][1], qfA[1], z, 0, 0, 0);
        bf16x4 qd;
#pragma unroll
        for (int r = 0; r < 4; ++r) qd[r] = (__bf16)__builtin_exp2f(z[r]);
        *(bf16x4*)(wbA + 32 * jt) = qd;
      }
#pragma unroll
      for (int jt = 0; jt < 4; ++jt) {
        f32x4 z = f32x4_zero();
        z = __builtin_amdgcn_mfma_f32_16x16x32_bf16(kv[jt][0], qfB[0], z, 0, 0, 0);
        z = __builtin_amdgcn_mfma_f32_16x16x32_bf16(kv[jt][1], qfB[1], z, 0, 0, 0);
        bf16x4 qd;
#pragma unroll
        for (int r = 0; r < 4; ++r) qd[r] = (__bf16)__builtin_exp2f(z[r]);
        *(bf16x4*)(wbB + 32 * jt) = qd;
      }
    } else {
      const int thrA = q0A + ln - kv0;
      const int thrB = q0B + ln - kv0;
#pragma unroll
      for (int jt = 0; jt < 4; ++jt) {
        f32x4 z = f32x4_zero();
        z = __builtin_amdgcn_mfma_f32_16x16x32_bf16(kv[jt][0], qfA[0], z, 0, 0, 0);
        z = __builtin_amdgcn_mfma_f32_16x16x32_bf16(kv[jt][1], qfA[1], z, 0, 0, 0);
        bf16x4 qd;
#pragma unroll
        for (int r = 0; r < 4; ++r) {
          float pv = __builtin_exp2f(z[r]);
          if (16 * jt + 4 * g + r > thrA) pv = 0.f;
          qd[r] = (__bf16)pv;
        }
        *(bf16x4*)(wbA + 32 * jt) = qd;
      }
#pragma unroll
      for (int jt = 0; jt < 4; ++jt) {
        f32x4 z = f32x4_zero();
        z = __builtin_amdgcn_mfma_f32_16x16x32_bf16(kv[jt][0], qfB[0], z, 0, 0, 0);
        z = __builtin_amdgcn_mfma_f32_16x16x32_bf16(kv[jt][1], qfB[1], z, 0, 0, 0);
        bf16x4 qd;
#pragma unroll
        for (int r = 0; r < 4; ++r) {
          float pv = __builtin_exp2f(z[r]);
          if (16 * jt + 4 * g + r > thrB) pv = 0.f;
          qd[r] = (__bf16)pv;
        }
        *(bf16x4*)(wbB + 32 * jt) = qd;
      }
    }

    // ---- load V tile into the SAME buffer (kf dead after QK) ----
#pragma unroll
    for (int nt = 0; nt < 4; ++nt)
#pragma unroll
      for (int ks = 0; ks < 2; ++ks)
        kv[nt][ks] = *(const bf16x8*)(vp + (size_t)16 * nt * S_LEN + 32 * ks);
    vp += 64;

    // ---- read P fragments ----
    bf16x8 paA0 = *(const bf16x8*)(rbA);
    bf16x8 paA1 = *(const bf16x8*)(rbA + 64);
    bf16x8 paB0 = *(const bf16x8*)(rbB);
    bf16x8 paB1 = *(const bf16x8*)(rbB + 64);

    // ---- PV (A and B) + row sums via ones ----
    __builtin_amdgcn_s_setprio(1);
    o5A = __builtin_amdgcn_mfma_f32_16x16x32_bf16(paA0, ones, o5A, 0, 0, 0);
    o5A = __builtin_amdgcn_mfma_f32_16x16x32_bf16(paA1, ones, o5A, 0, 0, 0);
    o5B = __builtin_amdgcn_mfma_f32_16x16x32_bf16(paB0, ones, o5B, 0, 0, 0);
    o5B = __builtin_amdgcn_mfma_f32_16x16x32_bf16(paB1, ones, o5B, 0, 0, 0);
#pragma unroll
    for (int nt = 0; nt < 4; ++nt) {
      oA[nt] = __builtin_amdgcn_mfma_f32_16x16x32_bf16(paA0, kv[nt][0], oA[nt], 0, 0, 0);
      oA[nt] = __builtin_amdgcn_mfma_f32_16x16x32_bf16(paA1, kv[nt][1], oA[nt], 0, 0, 0);
      oB[nt] = __builtin_amdgcn_mfma_f32_16x16x32_bf16(paB0, kv[nt][0], oB[nt], 0, 0, 0);
      oB[nt] = __builtin_amdgcn_mfma_f32_16x16x32_bf16(paB1, kv[nt][1], oB[nt], 0, 0, 0);
    }
    __builtin_amdgcn_s_setprio(0);
  }

  if (!split) {
    // direct write Y: lane holds O[q=4g+r][d=16nt+ln]
    const int bb = head / NH, hh = head - bb * NH;
    __bf16* Yp = Y + ((size_t)bb * S_LEN) * DMODEL + hh * HD;
#pragma unroll
    for (int r = 0; r < 4; ++r) {
      float lA = 1.0f / o5A[r];
      float lB = 1.0f / o5B[r];
      int qrA = q0A + 4 * g + r, qrB = q0B + 4 * g + r;
#pragma unroll
      for (int nt = 0; nt < 4; ++nt) {
        Yp[(size_t)qrA * DMODEL + 16 * nt + ln] = (__bf16)(oA[nt][r] * lA);
        Yp[(size_t)qrB * DMODEL + 16 * nt + ln] = (__bf16)(oB[nt][r] * lB);
      }
    }
  } else {
    // partial slab: O bf16 [32 rows][64 d] + rowsum f32 [32]
    char* oslab = Po + (size_t)(((head << 6) + (c - 64)) * 2 + part) * SLAB_STRIDE;
#pragma unroll
    for (int r = 0; r < 4; ++r) {
      int rowA = 4 * g + r, rowB = 16 + rowA;
#pragma unroll
      for (int nt = 0; nt < 4; ++nt) {
        *(__bf16*)(oslab + (rowA * 64 + 16 * nt + ln) * 2) = (__bf16)oA[nt][r];
        *(__bf16*)(oslab + (rowB * 64 + 16 * nt + ln) * 2) = (__bf16)oB[nt][r];
      }
      if (ln == 0) {
        *(float*)(oslab + 4096 + rowA * 4) = o5A[r];
        *(float*)(oslab + 4096 + rowB * 4) = o5B[r];
      }
    }
  }
}

// ---------------- combine split-chunk partials ----------------
__global__ __launch_bounds__(256) void attn_combine(const char* __restrict__ Po,
                                                    __bf16* __restrict__ Y) {
  const int blk = blockIdx.x;  // 0..1535 = (head, c-64)
  const int head = blk >> 6, cc = blk & 63, c = cc + 64;
  const char* s0 = Po + (size_t)(((head << 6) + cc) * 2) * SLAB_STRIDE;
  const char* s1 = s0 + SLAB_STRIDE;
  const int tid = threadIdx.x;
  const int row = tid >> 3, d0 = (tid & 7) * 8;

  bf16x8 a = *(const bf16x8*)(s0 + (row * 64 + d0) * 2);
  bf16x8 b = *(const bf16x8*)(s1 + (row * 64 + d0) * 2);
  float rs = *(const float*)(s0 + 4096 + row * 4) + *(const float*)(s1 + 4096 + row * 4);
  float inv = 1.0f / rs;

  const int bb = head / NH, hh = head - bb * NH;
  __bf16* yp = Y + ((size_t)bb * S_LEN + 32 * c + row) * DMODEL + hh * HD + d0;
  bf16x8 o;
#pragma unroll
  for (int j = 0; j < 8; ++j) o[j] = (__bf16)(((float)a[j] + (float)b[j]) * inv);
  *(bf16x8*)yp = o;
}

extern "C" void kernel_launch(void* const* d_in, const int* in_sizes, int n_in,
                              void* d_out, int out_size, void* d_ws, size_t ws_size,
                              hipStream_t stream) {
  const float* x = (const float*)d_in[0];
  const float* Wqkv = (const float*)d_in[1];
  const float* bqkv = (const float*)d_in[2];
  const float* Wout = (const float*)d_in[3];
  const float* bout = (const float*)d_in[4];
  float* out = (float*)d_out;

  char* ws = (char*)d_ws;
  size_t off = 0;
  auto take = [&](size_t bytes) {
    char* p = ws + off;
    off += bytes;
    return p;
  };
  const size_t MD2 = (size_t)MTOT * DMODEL * 2;
  __bf16* xb = (__bf16*)take(MD2);
  __bf16* Wqkv_t = (__bf16*)take((size_t)3 * DMODEL * DMODEL * 2);
  __bf16* Wout_t = (__bf16*)take((size_t)DMODEL * DMODEL * 2);
  __bf16* Qb = (__bf16*)take(MD2);
  __bf16* Kb = (__bf16*)take(MD2);
  __bf16* Vtb = (__bf16*)take(MD2);
  __bf16* Yb = (__bf16*)take(MD2);
  char* Po = take((size_t)3072 * SLAB_STRIDE);  // 24 heads x 64 chunks x 2 parts

  int n8 = MTOT * DMODEL / 8;
  cvt_f32_bf16<<<(n8 + 255) / 256, 256, 0, stream>>>(x, xb, n8);
  transpose_cvt<<<dim3(DMODEL / 64, 3 * DMODEL / 64), 256, 0, stream>>>(Wqkv, Wqkv_t, 3 * DMODEL);
  transpose_cvt<<<dim3(DMODEL / 64, DMODEL / 64), 256, 0, stream>>>(Wout, Wout_t, DMODEL);
  gemm_qkv<<<64 * (3 * DMODEL / 128), 256, 0, stream>>>(xb, Wqkv_t, bqkv, Qb, Kb, Vtb);
  attn_fwd11<<<1152, 256, 0, stream>>>(Qb, Kb, Vtb, Yb, Po);
  attn_combine<<<1536, 256, 0, stream>>>(Po, Yb);
  gemm_out<<<64 * (DMODEL / 128), 256, 0, stream>>>(Yb, Wout_t, bout, out);
}

// Round 12
// 192.712 us; speedup vs baseline: 1.7527x; 1.7527x over previous
//
#include <hip/hip_runtime.h>

#define S_LEN 4096
#define NH 12
#define HD 64
#define DMODEL 768
#define BATCH 2
#define MTOT (BATCH * S_LEN) /* 8192 */

typedef __bf16 bf16x8 __attribute__((ext_vector_type(8)));
typedef __bf16 bf16x4 __attribute__((ext_vector_type(4)));
typedef float f32x4 __attribute__((ext_vector_type(4)));
typedef float f32x8 __attribute__((ext_vector_type(8)));

#define SM_SCALE_LOG2E 0.18033688f /* 0.125 * log2(e), folded into Q at GEMM1 */

__device__ __forceinline__ f32x4 f32x4_zero() {
  f32x4 z = {0.f, 0.f, 0.f, 0.f};
  return z;
}

// ---------------- prep: f32 -> bf16 (vectorized) ----------------
__global__ __launch_bounds__(256) void cvt_f32_bf16(const float* __restrict__ in,
                                                    __bf16* __restrict__ out, int n8) {
  int i = blockIdx.x * 256 + threadIdx.x;
  if (i >= n8) return;
  f32x8 a = ((const f32x8*)in)[i];
  bf16x8 o;
#pragma unroll
  for (int j = 0; j < 8; ++j) o[j] = (__bf16)a[j];
  ((bf16x8*)out)[i] = o;
}

// ---------------- prep: transpose [768][N] f32 -> [N][768] bf16 ----------------
__global__ __launch_bounds__(256) void transpose_cvt(const float* __restrict__ in,
                                                     __bf16* __restrict__ out, int N) {
  __shared__ __bf16 t[64][72];  // padded
  int kb = blockIdx.x * 64, nb = blockIdx.y * 64;
  int c = threadIdx.x & 63, r0 = threadIdx.x >> 6;
#pragma unroll
  for (int i = 0; i < 16; ++i) {
    int r = r0 * 16 + i;
    t[c][r] = (__bf16)in[(size_t)(kb + r) * N + nb + c];
  }
  __syncthreads();
#pragma unroll
  for (int i = 0; i < 16; ++i) {
    int r = r0 * 16 + i;
    out[(size_t)(nb + r) * DMODEL + kb + c] = t[r][c];
  }
}

// ---------------- shared GEMM core: C[128x128] += A[128xK] * Bt[128xK]^T ----------------
__device__ __forceinline__ void gemm128_bt(const __bf16* __restrict__ A,
                                           const __bf16* __restrict__ Bt,
                                           int m0, int n0, int K,
                                           __bf16* Alds, __bf16* Blds,
                                           f32x4 acc[4][4]) {
  const int tid = threadIdx.x;
  const int l = tid & 63, w = tid >> 6;
  const int wr = w >> 1, wc = w & 1;
  const int g = l >> 4, ln = l & 15;
  for (int k0 = 0; k0 < K; k0 += 64) {
#pragma unroll
    for (int i = 0; i < 4; ++i) {
      int chunk = tid + i * 256;
      int row = chunk >> 3, cs = chunk & 7;
      int dst = row * 64 + ((cs ^ (row & 7)) << 3);
      *(bf16x8*)(Alds + dst) = *(const bf16x8*)(A + (size_t)(m0 + row) * K + k0 + cs * 8);
      *(bf16x8*)(Blds + dst) = *(const bf16x8*)(Bt + (size_t)(n0 + row) * K + k0 + cs * 8);
    }
    __syncthreads();
#pragma unroll
    for (int kk = 0; kk < 2; ++kk) {
      bf16x8 af[4], bfr[4];
#pragma unroll
      for (int mi = 0; mi < 4; ++mi) {
        int row = wr * 64 + mi * 16 + ln;
        af[mi] = *(const bf16x8*)(Alds + row * 64 + ((((kk << 2) + g) ^ (row & 7)) << 3));
      }
#pragma unroll
      for (int ni = 0; ni < 4; ++ni) {
        int row = wc * 64 + ni * 16 + ln;
        bfr[ni] = *(const bf16x8*)(Blds + row * 64 + ((((kk << 2) + g) ^ (row & 7)) << 3));
      }
#pragma unroll
      for (int mi = 0; mi < 4; ++mi)
#pragma unroll
        for (int ni = 0; ni < 4; ++ni)
          acc[mi][ni] =
              __builtin_amdgcn_mfma_f32_16x16x32_bf16(af[mi], bfr[ni], acc[mi][ni], 0, 0, 0);
    }
    __syncthreads();
  }
}

// ---------------- GEMM1: qkv = xb @ Wqkv + bqkv; Q pre-scaled by 0.125*log2e;
// scatter Q,K [B,H,S,Hd]; V transposed [B,H,Hd,S] ----------------
__global__ __launch_bounds__(256) void gemm_qkv(const __bf16* __restrict__ xb,
                                                const __bf16* __restrict__ Wt,
                                                const float* __restrict__ bqkv,
                                                __bf16* __restrict__ Qo,
                                                __bf16* __restrict__ Ko,
                                                __bf16* __restrict__ Vto) {
  __shared__ __bf16 Alds[128 * 64];
  __shared__ __bf16 Blds[128 * 64];
  int bm = blockIdx.x & 63, bn = blockIdx.x >> 6;
  int m0 = bm * 128, n0 = bn * 128;
  f32x4 acc[4][4];
#pragma unroll
  for (int i = 0; i < 4; ++i)
#pragma unroll
    for (int j = 0; j < 4; ++j) acc[i][j] = f32x4_zero();
  gemm128_bt(xb, Wt, m0, n0, DMODEL, Alds, Blds, acc);

  const int l = threadIdx.x & 63, w = threadIdx.x >> 6;
  const int wr = w >> 1, wc = w & 1, g = l >> 4, ln = l & 15;
#pragma unroll
  for (int ni = 0; ni < 4; ++ni) {
    int ncol = n0 + wc * 64 + ni * 16 + ln;
    int which = ncol / DMODEL;  // 0=q 1=k 2=v (uniform per 16-col fragment)
    int dd = ncol - which * DMODEL;
    int h = dd >> 6, hd = dd & 63;
    float bias = bqkv[ncol];
    if (which == 2) {
#pragma unroll
      for (int mi = 0; mi < 4; ++mi)
#pragma unroll
        for (int r = 0; r < 4; ++r) {
          int mrow = m0 + wr * 64 + mi * 16 + 4 * g + r;
          int b = mrow >> 12, s = mrow & (S_LEN - 1);
          float v = acc[mi][ni][r] + bias;
          Vto[(((size_t)(b * NH + h) * HD) + hd) * S_LEN + s] = (__bf16)v;
        }
    } else {
      __bf16* op = (which == 0) ? Qo : Ko;
      const float scl = (which == 0) ? SM_SCALE_LOG2E : 1.0f;
#pragma unroll
      for (int mi = 0; mi < 4; ++mi)
#pragma unroll
        for (int r = 0; r < 4; ++r) {
          int mrow = m0 + wr * 64 + mi * 16 + 4 * g + r;
          int b = mrow >> 12, s = mrow & (S_LEN - 1);
          float v = (acc[mi][ni][r] + bias) * scl;
          op[((((size_t)b * NH + h) * S_LEN) + s) * HD + hd] = (__bf16)v;
        }
    }
  }
}

// ---------------- GEMM2: out = Yb @ Wout + bout (fp32 out) ----------------
__global__ __launch_bounds__(256) void gemm_out(const __bf16* __restrict__ yb,
                                                const __bf16* __restrict__ Wt,
                                                const float* __restrict__ bout,
                                                float* __restrict__ out) {
  __shared__ __bf16 Alds[128 * 64];
  __shared__ __bf16 Blds[128 * 64];
  int bm = blockIdx.x & 63, bn = blockIdx.x >> 6;
  int m0 = bm * 128, n0 = bn * 128;
  f32x4 acc[4][4];
#pragma unroll
  for (int i = 0; i < 4; ++i)
#pragma unroll
    for (int j = 0; j < 4; ++j) acc[i][j] = f32x4_zero();
  gemm128_bt(yb, Wt, m0, n0, DMODEL, Alds, Blds, acc);

  const int l = threadIdx.x & 63, w = threadIdx.x >> 6;
  const int wr = w >> 1, wc = w & 1, g = l >> 4, ln = l & 15;
#pragma unroll
  for (int ni = 0; ni < 4; ++ni) {
    int ncol = n0 + wc * 64 + ni * 16 + ln;
    float bias = bout[ncol];
#pragma unroll
    for (int mi = 0; mi < 4; ++mi)
#pragma unroll
      for (int r = 0; r < 4; ++r) {
        int mrow = m0 + wr * 64 + mi * 16 + 4 * g + r;
        out[(size_t)mrow * DMODEL + ncol] = acc[mi][ni][r] + bias;
      }
  }
}

// ---------------- causal flash attention v12: cooperative LDS-shared ----------------
// Block = 4 waves sharing XOR-swizzled K/V tiles in LDS (64 kv x 64 d each),
// double-buffered, ONE barrier/iter; staging loads issued at iteration top
// (T14) so global latency hides under QK/softmax/PV. Wave = 16 q-rows
// (verified swapped-QK + P-bounce + ones-rowsum machinery; P pitch 128 + XOR).
// Block processes antithetic chunk pair (64-row chunks 63-p then p)
// SEQUENTIALLY -> every block runs exactly 65 iterations: perfect balance,
// 768 blocks = 3/CU all-resident, direct Y writes, no combine pass.
__global__ __launch_bounds__(256) void attn_fwd12(const __bf16* __restrict__ Q,
                                                  const __bf16* __restrict__ K,
                                                  const __bf16* __restrict__ Vt,
                                                  __bf16* __restrict__ Y) {
  __shared__ __bf16 KVl[2][2][4096];  // [buf][K/V][64 rows x 64 cols], swizzled
  __shared__ char Plb[4][2048];       // per-wave P bounce [16 q][64 kv] pitch 128 + XOR

  const int tid = threadIdx.x;
  const int wv = tid >> 6, l = tid & 63;
  const int g = l >> 4, ln = l & 15;
  const int bi = blockIdx.x;
  const int xcd = bi & 7, j = bi >> 3;  // j in 0..95
  const int head = xcd * 3 + (j % 3);   // 3 heads per XCD
  const int p = j / 3;                  // pair 0..31
  const int hc = 63 - p, lc = p;        // heavy / light 64-row chunk index
  const int thr = 16 * wv + ln;         // diag mask threshold (kv_off > q_off)

  const size_t hb = (size_t)head * (S_LEN * HD);
  const __bf16* Qh = Q + hb;
  const __bf16* Kh = K + hb;
  const __bf16* Vh = Vt + hb;  // [HD][S]

  const int q0H = 64 * hc + 16 * wv;
  const int q0L = 64 * lc + 16 * wv;

  // P bounce addressing (pitch 128 bytes, XOR granule swizzle)
  const int sw = (ln & 7) << 4;
  char* Pw = Plb[wv] + ln * 128;

  // cooperative staging geometry: 512 x 16B chunks per (K|V) tile
  const int c0 = tid, c1 = tid + 256;
  const int r0 = c0 >> 3, s0 = c0 & 7;
  const int r1 = c1 >> 3, s1 = c1 & 7;
  const int d0 = r0 * 64 + ((s0 ^ (r0 & 7)) << 3);
  const int d1 = r1 * 64 + ((s1 ^ (r1 & 7)) << 3);

  // Q fragments for both phases
  bf16x8 qfH[2], qfL[2];
#pragma unroll
  for (int t = 0; t < 2; ++t) {
    qfH[t] = *(const bf16x8*)(Qh + (size_t)(q0H + ln) * HD + 32 * t + 8 * g);
    qfL[t] = *(const bf16x8*)(Qh + (size_t)(q0L + ln) * HD + 32 * t + 8 * g);
  }

  bf16x8 ones;
#pragma unroll
  for (int t = 0; t < 8; ++t) ones[t] = (__bf16)1.0f;

  f32x4 o[4], o5;
#pragma unroll
  for (int nt = 0; nt < 4; ++nt) o[nt] = f32x4_zero();
  o5 = f32x4_zero();

  const int bb = head / NH, hh = head - bb * NH;
  __bf16* Yp = Y + ((size_t)bb * S_LEN) * DMODEL + hh * HD;

  // prologue: stage tile 0 into buf 0
  {
    bf16x8 ka0 = *(const bf16x8*)(Kh + c0 * 8);
    bf16x8 ka1 = *(const bf16x8*)(Kh + c1 * 8);
    bf16x8 va0 = *(const bf16x8*)(Vh + (size_t)r0 * S_LEN + s0 * 8);
    bf16x8 va1 = *(const bf16x8*)(Vh + (size_t)r1 * S_LEN + s1 * 8);
    *(bf16x8*)(&KVl[0][0][0] + d0) = ka0;
    *(bf16x8*)(&KVl[0][0][0] + d1) = ka1;
    *(bf16x8*)(&KVl[0][1][0] + d0) = va0;
    *(bf16x8*)(&KVl[0][1][0] + d1) = va1;
    __syncthreads();
  }

  int cur = 0;
  for (int i = 0; i < 65; ++i) {  // (hc+1) + (lc+1) = 65 always
    const bool more = (i + 1) < 65;
    // ---- issue next-tile global loads early (latency hides under compute) ----
    bf16x8 ka0, ka1, va0, va1;
    if (more) {
      int nx = i + 1;
      int tn = (nx <= hc) ? nx : nx - hc - 1;
      const __bf16* ks = Kh + (size_t)(tn * 64) * HD;
      const __bf16* vs = Vh + tn * 64;
      ka0 = *(const bf16x8*)(ks + c0 * 8);
      ka1 = *(const bf16x8*)(ks + c1 * 8);
      va0 = *(const bf16x8*)(vs + (size_t)r0 * S_LEN + s0 * 8);
      va1 = *(const bf16x8*)(vs + (size_t)r1 * S_LEN + s1 * 8);
    }

    const __bf16* Kl = &KVl[cur][0][0];
    const __bf16* Vl = &KVl[cur][1][0];
    const bool phL = (i > hc);
    const bool diag = (i == hc) || (i == 64);
    bf16x8 qf0 = phL ? qfL[0] : qfH[0];
    bf16x8 qf1 = phL ? qfL[1] : qfH[1];

    // ---- QK^T + fused softmax -> P bounce ----
    if (!diag) {
#pragma unroll
      for (int jt = 0; jt < 4; ++jt) {
        int row = 16 * jt + ln;
        bf16x8 kf0 = *(const bf16x8*)(Kl + row * 64 + ((g ^ (row & 7)) << 3));
        bf16x8 kf1 = *(const bf16x8*)(Kl + row * 64 + (((4 + g) ^ (row & 7)) << 3));
        f32x4 z = f32x4_zero();
        z = __builtin_amdgcn_mfma_f32_16x16x32_bf16(kf0, qf0, z, 0, 0, 0);
        z = __builtin_amdgcn_mfma_f32_16x16x32_bf16(kf1, qf1, z, 0, 0, 0);
        bf16x4 qd;
#pragma unroll
        for (int r = 0; r < 4; ++r) qd[r] = (__bf16)__builtin_exp2f(z[r]);
        *(bf16x4*)(Pw + ((32 * jt + 8 * g) ^ sw)) = qd;
      }
    } else {
#pragma unroll
      for (int jt = 0; jt < 4; ++jt) {
        int row = 16 * jt + ln;
        bf16x8 kf0 = *(const bf16x8*)(Kl + row * 64 + ((g ^ (row & 7)) << 3));
        bf16x8 kf1 = *(const bf16x8*)(Kl + row * 64 + (((4 + g) ^ (row & 7)) << 3));
        f32x4 z = f32x4_zero();
        z = __builtin_amdgcn_mfma_f32_16x16x32_bf16(kf0, qf0, z, 0, 0, 0);
        z = __builtin_amdgcn_mfma_f32_16x16x32_bf16(kf1, qf1, z, 0, 0, 0);
        bf16x4 qd;
#pragma unroll
        for (int r = 0; r < 4; ++r) {
          float pv = __builtin_exp2f(z[r]);
          if (16 * jt + 4 * g + r > thr) pv = 0.f;
          qd[r] = (__bf16)pv;
        }
        *(bf16x4*)(Pw + ((32 * jt + 8 * g) ^ sw)) = qd;
      }
    }

    // ---- PV + ones row-sum ----
    bf16x8 pa0 = *(const bf16x8*)(Pw + ((16 * g) ^ sw));
    bf16x8 pa1 = *(const bf16x8*)(Pw + ((64 + 16 * g) ^ sw));
    __builtin_amdgcn_s_setprio(1);
    o5 = __builtin_amdgcn_mfma_f32_16x16x32_bf16(pa0, ones, o5, 0, 0, 0);
    o5 = __builtin_amdgcn_mfma_f32_16x16x32_bf16(pa1, ones, o5, 0, 0, 0);
#pragma unroll
    for (int nt = 0; nt < 4; ++nt) {
      int row = 16 * nt + ln;
      bf16x8 vf0 = *(const bf16x8*)(Vl + row * 64 + ((g ^ (row & 7)) << 3));
      bf16x8 vf1 = *(const bf16x8*)(Vl + row * 64 + (((4 + g) ^ (row & 7)) << 3));
      o[nt] = __builtin_amdgcn_mfma_f32_16x16x32_bf16(pa0, vf0, o[nt], 0, 0, 0);
      o[nt] = __builtin_amdgcn_mfma_f32_16x16x32_bf16(pa1, vf1, o[nt], 0, 0, 0);
    }
    __builtin_amdgcn_s_setprio(0);

    // ---- phase end: write this chunk's output, reset accumulators ----
    if (diag) {
      const int q0 = phL ? q0L : q0H;  // i==hc: heavy; i==64: light
#pragma unroll
      for (int r = 0; r < 4; ++r) {
        float inv = 1.0f / o5[r];
        int qr = q0 + 4 * g + r;
#pragma unroll
        for (int nt = 0; nt < 4; ++nt)
          Yp[(size_t)qr * DMODEL + 16 * nt + ln] = (__bf16)(o[nt][r] * inv);
      }
#pragma unroll
      for (int nt = 0; nt < 4; ++nt) o[nt] = f32x4_zero();
      o5 = f32x4_zero();
    }

    // ---- write staged tile into the other buffer; single barrier ----
    if (more) {
      __bf16* Kd = &KVl[cur ^ 1][0][0];
      __bf16* Vd = &KVl[cur ^ 1][1][0];
      *(bf16x8*)(Kd + d0) = ka0;
      *(bf16x8*)(Kd + d1) = ka1;
      *(bf16x8*)(Vd + d0) = va0;
      *(bf16x8*)(Vd + d1) = va1;
      __syncthreads();
    }
    cur ^= 1;
  }
}

extern "C" void kernel_launch(void* const* d_in, const int* in_sizes, int n_in,
                              void* d_out, int out_size, void* d_ws, size_t ws_size,
                              hipStream_t stream) {
  const float* x = (const float*)d_in[0];
  const float* Wqkv = (const float*)d_in[1];
  const float* bqkv = (const float*)d_in[2];
  const float* Wout = (const float*)d_in[3];
  const float* bout = (const float*)d_in[4];
  float* out = (float*)d_out;

  char* ws = (char*)d_ws;
  size_t off = 0;
  auto take = [&](size_t bytes) {
    char* p = ws + off;
    off += bytes;
    return p;
  };
  const size_t MD2 = (size_t)MTOT * DMODEL * 2;
  __bf16* xb = (__bf16*)take(MD2);
  __bf16* Wqkv_t = (__bf16*)take((size_t)3 * DMODEL * DMODEL * 2);
  __bf16* Wout_t = (__bf16*)take((size_t)DMODEL * DMODEL * 2);
  __bf16* Qb = (__bf16*)take(MD2);
  __bf16* Kb = (__bf16*)take(MD2);
  __bf16* Vtb = (__bf16*)take(MD2);
  __bf16* Yb = (__bf16*)take(MD2);

  int n8 = MTOT * DMODEL / 8;
  cvt_f32_bf16<<<(n8 + 255) / 256, 256, 0, stream>>>(x, xb, n8);
  transpose_cvt<<<dim3(DMODEL / 64, 3 * DMODEL / 64), 256, 0, stream>>>(Wqkv, Wqkv_t, 3 * DMODEL);
  transpose_cvt<<<dim3(DMODEL / 64, DMODEL / 64), 256, 0, stream>>>(Wout, Wout_t, DMODEL);
  gemm_qkv<<<64 * (3 * DMODEL / 128), 256, 0, stream>>>(xb, Wqkv_t, bqkv, Qb, Kb, Vtb);
  attn_fwd12<<<768, 256, 0, stream>>>(Qb, Kb, Vtb, Yb);
  gemm_out<<<64 * (DMODEL / 128), 256, 0, stream>>>(Yb, Wout_t, bout, out);
}

// Round 13
// 186.120 us; speedup vs baseline: 1.8148x; 1.0354x over previous
//
#include <hip/hip_runtime.h>

#define S_LEN 4096
#define NH 12
#define HD 64
#define DMODEL 768
#define BATCH 2
#define MTOT (BATCH * S_LEN) /* 8192 */

typedef __bf16 bf16x8 __attribute__((ext_vector_type(8)));
typedef __bf16 bf16x4 __attribute__((ext_vector_type(4)));
typedef float f32x4 __attribute__((ext_vector_type(4)));
typedef float f32x8 __attribute__((ext_vector_type(8)));

#define SM_SCALE_LOG2E 0.18033688f /* 0.125 * log2(e), folded into Q at GEMM1 */

__device__ __forceinline__ f32x4 f32x4_zero() {
  f32x4 z = {0.f, 0.f, 0.f, 0.f};
  return z;
}

// async global->LDS DMA, 16B per lane. LDS dest = wave-uniform base + lane*16
// (linear); swizzled layouts are realized by pre-swizzling the per-lane GLOBAL
// source address (rule #21). Completion: drained by the vmcnt(0) the compiler
// emits before s_barrier (__syncthreads).
__device__ __forceinline__ void async16(const __bf16* g, void* l) {
  __builtin_amdgcn_global_load_lds(
      (const __attribute__((address_space(1))) void*)g,
      (__attribute__((address_space(3))) void*)l, 16, 0, 0);
}

// ---------------- prep: f32 -> bf16 (vectorized) ----------------
__global__ __launch_bounds__(256) void cvt_f32_bf16(const float* __restrict__ in,
                                                    __bf16* __restrict__ out, int n8) {
  int i = blockIdx.x * 256 + threadIdx.x;
  if (i >= n8) return;
  f32x8 a = ((const f32x8*)in)[i];
  bf16x8 o;
#pragma unroll
  for (int j = 0; j < 8; ++j) o[j] = (__bf16)a[j];
  ((bf16x8*)out)[i] = o;
}

// ---------------- prep: transpose [768][N] f32 -> [N][768] bf16 ----------------
__global__ __launch_bounds__(256) void transpose_cvt(const float* __restrict__ in,
                                                     __bf16* __restrict__ out, int N) {
  __shared__ __bf16 t[64][72];  // padded
  int kb = blockIdx.x * 64, nb = blockIdx.y * 64;
  int c = threadIdx.x & 63, r0 = threadIdx.x >> 6;
#pragma unroll
  for (int i = 0; i < 16; ++i) {
    int r = r0 * 16 + i;
    t[c][r] = (__bf16)in[(size_t)(kb + r) * N + nb + c];
  }
  __syncthreads();
#pragma unroll
  for (int i = 0; i < 16; ++i) {
    int r = r0 * 16 + i;
    out[(size_t)(nb + r) * DMODEL + kb + c] = t[r][c];
  }
}

// ---------------- shared GEMM core: C[128x128] += A[128xK] * Bt[128xK]^T ----------------
// Staging now via global_load_lds (width 16): linear LDS dest, inverse-swizzled
// global source; read-side swizzle unchanged from the verified v12 layout.
__device__ __forceinline__ void gemm128_bt(const __bf16* __restrict__ A,
                                           const __bf16* __restrict__ Bt,
                                           int m0, int n0, int K,
                                           __bf16* Alds, __bf16* Blds,
                                           f32x4 acc[4][4]) {
  const int tid = threadIdx.x;
  const int l = tid & 63, w = tid >> 6;
  const int wr = w >> 1, wc = w & 1;
  const int g = l >> 4, ln = l & 15;

  // staging lane geometry: chunk c = i*256 + tid; row = i*32 + (tid>>3);
  // linear LDS granule gd = tid&7 holds source slot s = gd ^ (row&7).
  const int rr = tid >> 3;
  const int sx = (tid & 7) ^ (rr & 7);
  const __bf16* As = A + (size_t)(m0 + rr) * K + sx * 8;
  const __bf16* Bs = Bt + (size_t)(n0 + rr) * K + sx * 8;
  char* Ad = (char*)Alds + (w << 10);
  char* Bd = (char*)Blds + (w << 10);

  for (int k0 = 0; k0 < K; k0 += 64) {
#pragma unroll
    for (int i = 0; i < 4; ++i) {
      async16(As + (size_t)(i * 32) * K + k0, Ad + i * 4096);
      async16(Bs + (size_t)(i * 32) * K + k0, Bd + i * 4096);
    }
    __syncthreads();
#pragma unroll
    for (int kk = 0; kk < 2; ++kk) {
      bf16x8 af[4], bfr[4];
#pragma unroll
      for (int mi = 0; mi < 4; ++mi) {
        int row = wr * 64 + mi * 16 + ln;
        af[mi] = *(const bf16x8*)(Alds + row * 64 + ((((kk << 2) + g) ^ (row & 7)) << 3));
      }
#pragma unroll
      for (int ni = 0; ni < 4; ++ni) {
        int row = wc * 64 + ni * 16 + ln;
        bfr[ni] = *(const bf16x8*)(Blds + row * 64 + ((((kk << 2) + g) ^ (row & 7)) << 3));
      }
#pragma unroll
      for (int mi = 0; mi < 4; ++mi)
#pragma unroll
        for (int ni = 0; ni < 4; ++ni)
          acc[mi][ni] =
              __builtin_amdgcn_mfma_f32_16x16x32_bf16(af[mi], bfr[ni], acc[mi][ni], 0, 0, 0);
    }
    __syncthreads();
  }
}

// ---------------- GEMM1: qkv = xb @ Wqkv + bqkv; Q pre-scaled by 0.125*log2e;
// scatter Q,K [B,H,S,Hd]; V transposed [B,H,Hd,S] ----------------
__global__ __launch_bounds__(256) void gemm_qkv(const __bf16* __restrict__ xb,
                                                const __bf16* __restrict__ Wt,
                                                const float* __restrict__ bqkv,
                                                __bf16* __restrict__ Qo,
                                                __bf16* __restrict__ Ko,
                                                __bf16* __restrict__ Vto) {
  __shared__ __bf16 Alds[128 * 64];
  __shared__ __bf16 Blds[128 * 64];
  int bm = blockIdx.x & 63, bn = blockIdx.x >> 6;
  int m0 = bm * 128, n0 = bn * 128;
  f32x4 acc[4][4];
#pragma unroll
  for (int i = 0; i < 4; ++i)
#pragma unroll
    for (int j = 0; j < 4; ++j) acc[i][j] = f32x4_zero();
  gemm128_bt(xb, Wt, m0, n0, DMODEL, Alds, Blds, acc);

  const int l = threadIdx.x & 63, w = threadIdx.x >> 6;
  const int wr = w >> 1, wc = w & 1, g = l >> 4, ln = l & 15;
#pragma unroll
  for (int ni = 0; ni < 4; ++ni) {
    int ncol = n0 + wc * 64 + ni * 16 + ln;
    int which = ncol / DMODEL;  // 0=q 1=k 2=v (uniform per 16-col fragment)
    int dd = ncol - which * DMODEL;
    int h = dd >> 6, hd = dd & 63;
    float bias = bqkv[ncol];
    if (which == 2) {
#pragma unroll
      for (int mi = 0; mi < 4; ++mi)
#pragma unroll
        for (int r = 0; r < 4; ++r) {
          int mrow = m0 + wr * 64 + mi * 16 + 4 * g + r;
          int b = mrow >> 12, s = mrow & (S_LEN - 1);
          float v = acc[mi][ni][r] + bias;
          Vto[(((size_t)(b * NH + h) * HD) + hd) * S_LEN + s] = (__bf16)v;
        }
    } else {
      __bf16* op = (which == 0) ? Qo : Ko;
      const float scl = (which == 0) ? SM_SCALE_LOG2E : 1.0f;
#pragma unroll
      for (int mi = 0; mi < 4; ++mi)
#pragma unroll
        for (int r = 0; r < 4; ++r) {
          int mrow = m0 + wr * 64 + mi * 16 + 4 * g + r;
          int b = mrow >> 12, s = mrow & (S_LEN - 1);
          float v = (acc[mi][ni][r] + bias) * scl;
          op[((((size_t)b * NH + h) * S_LEN) + s) * HD + hd] = (__bf16)v;
        }
    }
  }
}

// ---------------- GEMM2: out = Yb @ Wout + bout (fp32 out) ----------------
__global__ __launch_bounds__(256) void gemm_out(const __bf16* __restrict__ yb,
                                                const __bf16* __restrict__ Wt,
                                                const float* __restrict__ bout,
                                                float* __restrict__ out) {
  __shared__ __bf16 Alds[128 * 64];
  __shared__ __bf16 Blds[128 * 64];
  int bm = blockIdx.x & 63, bn = blockIdx.x >> 6;
  int m0 = bm * 128, n0 = bn * 128;
  f32x4 acc[4][4];
#pragma unroll
  for (int i = 0; i < 4; ++i)
#pragma unroll
    for (int j = 0; j < 4; ++j) acc[i][j] = f32x4_zero();
  gemm128_bt(yb, Wt, m0, n0, DMODEL, Alds, Blds, acc);

  const int l = threadIdx.x & 63, w = threadIdx.x >> 6;
  const int wr = w >> 1, wc = w & 1, g = l >> 4, ln = l & 15;
#pragma unroll
  for (int ni = 0; ni < 4; ++ni) {
    int ncol = n0 + wc * 64 + ni * 16 + ln;
    float bias = bout[ncol];
#pragma unroll
    for (int mi = 0; mi < 4; ++mi)
#pragma unroll
      for (int r = 0; r < 4; ++r) {
        int mrow = m0 + wr * 64 + mi * 16 + 4 * g + r;
        out[(size_t)mrow * DMODEL + ncol] = acc[mi][ni][r] + bias;
      }
  }
}

// ---------------- causal flash attention v13: v12 + global_load_lds staging ----------------
// v12's cooperative structure (4 waves share swizzled K/V LDS tiles, double-
// buffered, one barrier/iter, antithetic 65-iter chunk pairs, direct Y writes)
// with staging via global_load_lds: no reg round-trip, no ds_writes, rolling
// per-lane source pointers (2 adds/iter of address VALU).
__global__ __launch_bounds__(256) void attn_fwd13(const __bf16* __restrict__ Q,
                                                  const __bf16* __restrict__ K,
                                                  const __bf16* __restrict__ Vt,
                                                  __bf16* __restrict__ Y) {
  __shared__ __bf16 KVl[2][2][4096];  // [buf][K/V][64 rows x 64 cols], swizzled
  __shared__ char Plb[4][2048];       // per-wave P bounce [16 q][64 kv] pitch 128 + XOR

  const int tid = threadIdx.x;
  const int wv = tid >> 6, l = tid & 63;
  const int g = l >> 4, ln = l & 15;
  const int bi = blockIdx.x;
  const int xcd = bi & 7, j = bi >> 3;  // j in 0..95
  const int head = xcd * 3 + (j % 3);   // 3 heads per XCD
  const int p = j / 3;                  // pair 0..31
  const int hc = 63 - p;                // heavy chunk; light chunk = p
  const int thr = 16 * wv + ln;         // diag mask threshold

  const size_t hb = (size_t)head * (S_LEN * HD);
  const __bf16* Qh = Q + hb;
  const __bf16* Kh = K + hb;
  const __bf16* Vh = Vt + hb;  // [HD][S]

  const int q0H = 64 * hc + 16 * wv;
  const int q0L = 64 * p + 16 * wv;

  const int sw = (ln & 7) << 4;
  char* Pw = Plb[wv] + ln * 128;

  // staging lane geometry: chunk c0=tid, c1=tid+256; row=c>>3; linear granule
  // gd=c&7 receives source slot s = gd ^ (row&7)  (row&7 identical for c0,c1)
  const int r0 = tid >> 3;
  const int s0 = (tid & 7) ^ (r0 & 7);
  const size_t kL0 = (size_t)r0 * HD + s0 * 8;
  const size_t kL1 = kL0 + (size_t)32 * HD;
  const size_t vL0 = (size_t)r0 * S_LEN + s0 * 8;
  const size_t vL1 = vL0 + (size_t)32 * S_LEN;
  const int ldsoff = wv << 10;  // wave's 1KB slice of each 4KB half

  bf16x8 qfH[2], qfL[2];
#pragma unroll
  for (int t = 0; t < 2; ++t) {
    qfH[t] = *(const bf16x8*)(Qh + (size_t)(q0H + ln) * HD + 32 * t + 8 * g);
    qfL[t] = *(const bf16x8*)(Qh + (size_t)(q0L + ln) * HD + 32 * t + 8 * g);
  }

  bf16x8 ones;
#pragma unroll
  for (int t = 0; t < 8; ++t) ones[t] = (__bf16)1.0f;

  f32x4 o[4], o5;
#pragma unroll
  for (int nt = 0; nt < 4; ++nt) o[nt] = f32x4_zero();
  o5 = f32x4_zero();

  const int bb = head / NH, hh = head - bb * NH;
  __bf16* Yp = Y + ((size_t)bb * S_LEN) * DMODEL + hh * HD;

  // prologue: stage tile 0 into buf 0
  {
    char* Kd = (char*)&KVl[0][0][0] + ldsoff;
    char* Vd = (char*)&KVl[0][1][0] + ldsoff;
    async16(Kh + kL0, Kd);
    async16(Kh + kL1, Kd + 4096);
    async16(Vh + vL0, Vd);
    async16(Vh + vL1, Vd + 4096);
    __syncthreads();
  }
  const __bf16* kq = Kh + 64 * HD;  // next K tile base
  const __bf16* vq = Vh + 64;       // next V tile base

  int cur = 0;
  for (int i = 0; i < 65; ++i) {  // (hc+1) + (lc+1) = 65 always
    const bool more = i < 64;
    // ---- issue next-tile DMA into buf^1 (drained by end-of-iter barrier) ----
    if (more) {
      if (i == hc) {  // next tile = light-phase tile 0
        kq = Kh;
        vq = Vh;
      }
      char* Kd = (char*)&KVl[cur ^ 1][0][0] + ldsoff;
      char* Vd = (char*)&KVl[cur ^ 1][1][0] + ldsoff;
      async16(kq + kL0, Kd);
      async16(kq + kL1, Kd + 4096);
      async16(vq + vL0, Vd);
      async16(vq + vL1, Vd + 4096);
      kq += (size_t)64 * HD;
      vq += 64;
    }

    const __bf16* Kl = &KVl[cur][0][0];
    const __bf16* Vl = &KVl[cur][1][0];
    const bool phL = (i > hc);
    const bool diag = (i == hc) || (i == 64);
    bf16x8 qf0 = phL ? qfL[0] : qfH[0];
    bf16x8 qf1 = phL ? qfL[1] : qfH[1];

    // ---- QK^T + fused softmax -> P bounce ----
    if (!diag) {
#pragma unroll
      for (int jt = 0; jt < 4; ++jt) {
        int row = 16 * jt + ln;
        bf16x8 kf0 = *(const bf16x8*)(Kl + row * 64 + ((g ^ (row & 7)) << 3));
        bf16x8 kf1 = *(const bf16x8*)(Kl + row * 64 + (((4 + g) ^ (row & 7)) << 3));
        f32x4 z = f32x4_zero();
        z = __builtin_amdgcn_mfma_f32_16x16x32_bf16(kf0, qf0, z, 0, 0, 0);
        z = __builtin_amdgcn_mfma_f32_16x16x32_bf16(kf1, qf1, z, 0, 0, 0);
        bf16x4 qd;
#pragma unroll
        for (int r = 0; r < 4; ++r) qd[r] = (__bf16)__builtin_exp2f(z[r]);
        *(bf16x4*)(Pw + ((32 * jt + 8 * g) ^ sw)) = qd;
      }
    } else {
#pragma unroll
      for (int jt = 0; jt < 4; ++jt) {
        int row = 16 * jt + ln;
        bf16x8 kf0 = *(const bf16x8*)(Kl + row * 64 + ((g ^ (row & 7)) << 3));
        bf16x8 kf1 = *(const bf16x8*)(Kl + row * 64 + (((4 + g) ^ (row & 7)) << 3));
        f32x4 z = f32x4_zero();
        z = __builtin_amdgcn_mfma_f32_16x16x32_bf16(kf0, qf0, z, 0, 0, 0);
        z = __builtin_amdgcn_mfma_f32_16x16x32_bf16(kf1, qf1, z, 0, 0, 0);
        bf16x4 qd;
#pragma unroll
        for (int r = 0; r < 4; ++r) {
          float pv = __builtin_exp2f(z[r]);
          if (16 * jt + 4 * g + r > thr) pv = 0.f;
          qd[r] = (__bf16)pv;
        }
        *(bf16x4*)(Pw + ((32 * jt + 8 * g) ^ sw)) = qd;
      }
    }

    // ---- PV + ones row-sum ----
    bf16x8 pa0 = *(const bf16x8*)(Pw + ((16 * g) ^ sw));
    bf16x8 pa1 = *(const bf16x8*)(Pw + ((64 + 16 * g) ^ sw));
    __builtin_amdgcn_s_setprio(1);
    o5 = __builtin_amdgcn_mfma_f32_16x16x32_bf16(pa0, ones, o5, 0, 0, 0);
    o5 = __builtin_amdgcn_mfma_f32_16x16x32_bf16(pa1, ones, o5, 0, 0, 0);
#pragma unroll
    for (int nt = 0; nt < 4; ++nt) {
      int row = 16 * nt + ln;
      bf16x8 vf0 = *(const bf16x8*)(Vl + row * 64 + ((g ^ (row & 7)) << 3));
      bf16x8 vf1 = *(const bf16x8*)(Vl + row * 64 + (((4 + g) ^ (row & 7)) << 3));
      o[nt] = __builtin_amdgcn_mfma_f32_16x16x32_bf16(pa0, vf0, o[nt], 0, 0, 0);
      o[nt] = __builtin_amdgcn_mfma_f32_16x16x32_bf16(pa1, vf1, o[nt], 0, 0, 0);
    }
    __builtin_amdgcn_s_setprio(0);

    // ---- phase end: write chunk output, reset accumulators ----
    if (diag) {
      const int q0 = phL ? q0L : q0H;
#pragma unroll
      for (int r = 0; r < 4; ++r) {
        float inv = 1.0f / o5[r];
        int qr = q0 + 4 * g + r;
#pragma unroll
        for (int nt = 0; nt < 4; ++nt)
          Yp[(size_t)qr * DMODEL + 16 * nt + ln] = (__bf16)(o[nt][r] * inv);
      }
#pragma unroll
      for (int nt = 0; nt < 4; ++nt) o[nt] = f32x4_zero();
      o5 = f32x4_zero();
    }

    if (more) __syncthreads();  // drains DMA (vmcnt0) + publishes buf^1
    cur ^= 1;
  }
}

extern "C" void kernel_launch(void* const* d_in, const int* in_sizes, int n_in,
                              void* d_out, int out_size, void* d_ws, size_t ws_size,
                              hipStream_t stream) {
  const float* x = (const float*)d_in[0];
  const float* Wqkv = (const float*)d_in[1];
  const float* bqkv = (const float*)d_in[2];
  const float* Wout = (const float*)d_in[3];
  const float* bout = (const float*)d_in[4];
  float* out = (float*)d_out;

  char* ws = (char*)d_ws;
  size_t off = 0;
  auto take = [&](size_t bytes) {
    char* p = ws + off;
    off += bytes;
    return p;
  };
  const size_t MD2 = (size_t)MTOT * DMODEL * 2;
  __bf16* xb = (__bf16*)take(MD2);
  __bf16* Wqkv_t = (__bf16*)take((size_t)3 * DMODEL * DMODEL * 2);
  __bf16* Wout_t = (__bf16*)take((size_t)DMODEL * DMODEL * 2);
  __bf16* Qb = (__bf16*)take(MD2);
  __bf16* Kb = (__bf16*)take(MD2);
  __bf16* Vtb = (__bf16*)take(MD2);
  __bf16* Yb = (__bf16*)take(MD2);

  int n8 = MTOT * DMODEL / 8;
  cvt_f32_bf16<<<(n8 + 255) / 256, 256, 0, stream>>>(x, xb, n8);
  transpose_cvt<<<dim3(DMODEL / 64, 3 * DMODEL / 64), 256, 0, stream>>>(Wqkv, Wqkv_t, 3 * DMODEL);
  transpose_cvt<<<dim3(DMODEL / 64, DMODEL / 64), 256, 0, stream>>>(Wout, Wout_t, DMODEL);
  gemm_qkv<<<64 * (3 * DMODEL / 128), 256, 0, stream>>>(xb, Wqkv_t, bqkv, Qb, Kb, Vtb);
  attn_fwd13<<<768, 256, 0, stream>>>(Qb, Kb, Vtb, Yb);
  gemm_out<<<64 * (DMODEL / 128), 256, 0, stream>>>(Yb, Wout_t, bout, out);
}

// Round 14
// 183.224 us; speedup vs baseline: 1.8435x; 1.0158x over previous
//
#include <hip/hip_runtime.h>

#define S_LEN 4096
#define NH 12
#define HD 64
#define DMODEL 768
#define BATCH 2
#define MTOT (BATCH * S_LEN) /* 8192 */

typedef __bf16 bf16x8 __attribute__((ext_vector_type(8)));
typedef __bf16 bf16x4 __attribute__((ext_vector_type(4)));
typedef float f32x4 __attribute__((ext_vector_type(4)));
typedef float f32x8 __attribute__((ext_vector_type(8)));

#define SM_SCALE_LOG2E 0.18033688f /* 0.125 * log2(e), folded into Q at GEMM1 */
#define SLAB_STRIDE 8448           /* 64x64 bf16 O (8192) + 64 f32 rowsum (256) */

__device__ __forceinline__ f32x4 f32x4_zero() {
  f32x4 z = {0.f, 0.f, 0.f, 0.f};
  return z;
}

// async global->LDS DMA, 16B per lane. LDS dest = wave-uniform base + lane*16
// (linear); swizzled layouts realized by pre-swizzling the per-lane GLOBAL
// source address (rule #21). Drained by the vmcnt(0) before s_barrier.
__device__ __forceinline__ void async16(const __bf16* g, void* l) {
  __builtin_amdgcn_global_load_lds(
      (const __attribute__((address_space(1))) void*)g,
      (__attribute__((address_space(3))) void*)l, 16, 0, 0);
}

// ---------------- prep: f32 -> bf16 (vectorized) ----------------
__global__ __launch_bounds__(256) void cvt_f32_bf16(const float* __restrict__ in,
                                                    __bf16* __restrict__ out, int n8) {
  int i = blockIdx.x * 256 + threadIdx.x;
  if (i >= n8) return;
  f32x8 a = ((const f32x8*)in)[i];
  bf16x8 o;
#pragma unroll
  for (int j = 0; j < 8; ++j) o[j] = (__bf16)a[j];
  ((bf16x8*)out)[i] = o;
}

// ---------------- prep: transpose [768][N] f32 -> [N][768] bf16 ----------------
__global__ __launch_bounds__(256) void transpose_cvt(const float* __restrict__ in,
                                                     __bf16* __restrict__ out, int N) {
  __shared__ __bf16 t[64][72];  // padded
  int kb = blockIdx.x * 64, nb = blockIdx.y * 64;
  int c = threadIdx.x & 63, r0 = threadIdx.x >> 6;
#pragma unroll
  for (int i = 0; i < 16; ++i) {
    int r = r0 * 16 + i;
    t[c][r] = (__bf16)in[(size_t)(kb + r) * N + nb + c];
  }
  __syncthreads();
#pragma unroll
  for (int i = 0; i < 16; ++i) {
    int r = r0 * 16 + i;
    out[(size_t)(nb + r) * DMODEL + kb + c] = t[r][c];
  }
}

// ---------------- shared GEMM core: C[128x128] += A[128xK] * Bt[128xK]^T ----------------
__device__ __forceinline__ void gemm128_bt(const __bf16* __restrict__ A,
                                           const __bf16* __restrict__ Bt,
                                           int m0, int n0, int K,
                                           __bf16* Alds, __bf16* Blds,
                                           f32x4 acc[4][4]) {
  const int tid = threadIdx.x;
  const int l = tid & 63, w = tid >> 6;
  const int wr = w >> 1, wc = w & 1;
  const int g = l >> 4, ln = l & 15;

  const int rr = tid >> 3;
  const int sx = (tid & 7) ^ (rr & 7);
  const __bf16* As = A + (size_t)(m0 + rr) * K + sx * 8;
  const __bf16* Bs = Bt + (size_t)(n0 + rr) * K + sx * 8;
  char* Ad = (char*)Alds + (w << 10);
  char* Bd = (char*)Blds + (w << 10);

  for (int k0 = 0; k0 < K; k0 += 64) {
#pragma unroll
    for (int i = 0; i < 4; ++i) {
      async16(As + (size_t)(i * 32) * K + k0, Ad + i * 4096);
      async16(Bs + (size_t)(i * 32) * K + k0, Bd + i * 4096);
    }
    __syncthreads();
#pragma unroll
    for (int kk = 0; kk < 2; ++kk) {
      bf16x8 af[4], bfr[4];
#pragma unroll
      for (int mi = 0; mi < 4; ++mi) {
        int row = wr * 64 + mi * 16 + ln;
        af[mi] = *(const bf16x8*)(Alds + row * 64 + ((((kk << 2) + g) ^ (row & 7)) << 3));
      }
#pragma unroll
      for (int ni = 0; ni < 4; ++ni) {
        int row = wc * 64 + ni * 16 + ln;
        bfr[ni] = *(const bf16x8*)(Blds + row * 64 + ((((kk << 2) + g) ^ (row & 7)) << 3));
      }
#pragma unroll
      for (int mi = 0; mi < 4; ++mi)
#pragma unroll
        for (int ni = 0; ni < 4; ++ni)
          acc[mi][ni] =
              __builtin_amdgcn_mfma_f32_16x16x32_bf16(af[mi], bfr[ni], acc[mi][ni], 0, 0, 0);
    }
    __syncthreads();
  }
}

// ---------------- GEMM1: qkv = xb @ Wqkv + bqkv; Q pre-scaled by 0.125*log2e;
// scatter Q,K [B,H,S,Hd]; V transposed [B,H,Hd,S] ----------------
__global__ __launch_bounds__(256) void gemm_qkv(const __bf16* __restrict__ xb,
                                                const __bf16* __restrict__ Wt,
                                                const float* __restrict__ bqkv,
                                                __bf16* __restrict__ Qo,
                                                __bf16* __restrict__ Ko,
                                                __bf16* __restrict__ Vto) {
  __shared__ __bf16 Alds[128 * 64];
  __shared__ __bf16 Blds[128 * 64];
  int bm = blockIdx.x & 63, bn = blockIdx.x >> 6;
  int m0 = bm * 128, n0 = bn * 128;
  f32x4 acc[4][4];
#pragma unroll
  for (int i = 0; i < 4; ++i)
#pragma unroll
    for (int j = 0; j < 4; ++j) acc[i][j] = f32x4_zero();
  gemm128_bt(xb, Wt, m0, n0, DMODEL, Alds, Blds, acc);

  const int l = threadIdx.x & 63, w = threadIdx.x >> 6;
  const int wr = w >> 1, wc = w & 1, g = l >> 4, ln = l & 15;
#pragma unroll
  for (int ni = 0; ni < 4; ++ni) {
    int ncol = n0 + wc * 64 + ni * 16 + ln;
    int which = ncol / DMODEL;  // 0=q 1=k 2=v (uniform per 16-col fragment)
    int dd = ncol - which * DMODEL;
    int h = dd >> 6, hd = dd & 63;
    float bias = bqkv[ncol];
    if (which == 2) {
#pragma unroll
      for (int mi = 0; mi < 4; ++mi)
#pragma unroll
        for (int r = 0; r < 4; ++r) {
          int mrow = m0 + wr * 64 + mi * 16 + 4 * g + r;
          int b = mrow >> 12, s = mrow & (S_LEN - 1);
          float v = acc[mi][ni][r] + bias;
          Vto[(((size_t)(b * NH + h) * HD) + hd) * S_LEN + s] = (__bf16)v;
        }
    } else {
      __bf16* op = (which == 0) ? Qo : Ko;
      const float scl = (which == 0) ? SM_SCALE_LOG2E : 1.0f;
#pragma unroll
      for (int mi = 0; mi < 4; ++mi)
#pragma unroll
        for (int r = 0; r < 4; ++r) {
          int mrow = m0 + wr * 64 + mi * 16 + 4 * g + r;
          int b = mrow >> 12, s = mrow & (S_LEN - 1);
          float v = (acc[mi][ni][r] + bias) * scl;
          op[((((size_t)b * NH + h) * S_LEN) + s) * HD + hd] = (__bf16)v;
        }
    }
  }
}

// ---------------- GEMM2: out = Yb @ Wout + bout (fp32 out) ----------------
__global__ __launch_bounds__(256) void gemm_out(const __bf16* __restrict__ yb,
                                                const __bf16* __restrict__ Wt,
                                                const float* __restrict__ bout,
                                                float* __restrict__ out) {
  __shared__ __bf16 Alds[128 * 64];
  __shared__ __bf16 Blds[128 * 64];
  int bm = blockIdx.x & 63, bn = blockIdx.x >> 6;
  int m0 = bm * 128, n0 = bn * 128;
  f32x4 acc[4][4];
#pragma unroll
  for (int i = 0; i < 4; ++i)
#pragma unroll
    for (int j = 0; j < 4; ++j) acc[i][j] = f32x4_zero();
  gemm128_bt(yb, Wt, m0, n0, DMODEL, Alds, Blds, acc);

  const int l = threadIdx.x & 63, w = threadIdx.x >> 6;
  const int wr = w >> 1, wc = w & 1, g = l >> 4, ln = l & 15;
#pragma unroll
  for (int ni = 0; ni < 4; ++ni) {
    int ncol = n0 + wc * 64 + ni * 16 + ln;
    float bias = bout[ncol];
#pragma unroll
    for (int mi = 0; mi < 4; ++mi)
#pragma unroll
      for (int r = 0; r < 4; ++r) {
        int mrow = m0 + wr * 64 + mi * 16 + 4 * g + r;
        out[(size_t)mrow * DMODEL + ncol] = acc[mi][ni][r] + bias;
      }
  }
}

// ---------------- causal flash attention v14: v13 body + kv-split units ----------------
// v13's cooperative iteration body (4 waves share swizzled K/V LDS via
// global_load_lds DMA, double-buffered, one barrier/iter). Decomposition:
// unit = (head, 64-row chunk c, kv-part). Chunks c>=32 split into two kv
// halves -> partial slabs (exact: fixed-shift softmax partials add);
// chunks c<32 direct-write. 2304 units, ALL <=32 iterations (half v13's 65
// critical path), heavy-first; LDS 40KB -> 4 resident blocks/CU (v13 was
// grid-capped at 3).
__global__ __launch_bounds__(256) void attn_fwd14(const __bf16* __restrict__ Q,
                                                  const __bf16* __restrict__ K,
                                                  const __bf16* __restrict__ Vt,
                                                  __bf16* __restrict__ Y,
                                                  char* __restrict__ Po) {
  __shared__ __bf16 KVl[2][2][4096];  // [buf][K/V][64 rows x 64 cols], swizzled
  __shared__ char Plb[4][2048];       // per-wave P bounce [16 q][64 kv] pitch 128 + XOR

  const int tid = threadIdx.x;
  const int wv = tid >> 6, l = tid & 63;
  const int g = l >> 4, ln = l & 15;
  const int bi = blockIdx.x;
  const int xcd = bi & 7, j = bi >> 3;  // j in 0..287
  const int head = xcd * 3 + (j % 3);   // 3 heads per XCD
  const int r_ = j / 3;                 // rank 0..95, heavy-first

  int c, t0, t1, part;
  bool split;
  if (r_ < 64) {  // split chunks c=63..32, two kv halves each
    c = 63 - (r_ >> 1);
    part = r_ & 1;
    int T = c + 1;          // kv tiles in chunk
    int h = (T + 1) >> 1;   // part0 size
    t0 = part ? h : 0;
    t1 = part ? T : h;
    split = true;
  } else {  // direct chunks c=31..0
    c = 95 - r_;
    part = 0;
    t0 = 0;
    t1 = c + 1;
    split = false;
  }
  const int q0 = 64 * c + 16 * wv;
  const int thr = 16 * wv + ln;          // diag mask (chunk-local)
  const bool hasDiag = (t1 == c + 1);    // last tile of chunk in this unit

  const size_t hb = (size_t)head * (S_LEN * HD);
  const __bf16* Qh = Q + hb;
  const __bf16* Kh = K + hb;
  const __bf16* Vh = Vt + hb;  // [HD][S]

  const int sw = (ln & 7) << 4;
  char* Pw = Plb[wv] + ln * 128;

  // staging lane geometry (identical to v13)
  const int r0 = tid >> 3;
  const int s0 = (tid & 7) ^ (r0 & 7);
  const size_t kL0 = (size_t)r0 * HD + s0 * 8;
  const size_t kL1 = kL0 + (size_t)32 * HD;
  const size_t vL0 = (size_t)r0 * S_LEN + s0 * 8;
  const size_t vL1 = vL0 + (size_t)32 * S_LEN;
  const int ldsoff = wv << 10;

  bf16x8 qf[2];
#pragma unroll
  for (int t = 0; t < 2; ++t)
    qf[t] = *(const bf16x8*)(Qh + (size_t)(q0 + ln) * HD + 32 * t + 8 * g);

  bf16x8 ones;
#pragma unroll
  for (int t = 0; t < 8; ++t) ones[t] = (__bf16)1.0f;

  f32x4 o[4], o5;
#pragma unroll
  for (int nt = 0; nt < 4; ++nt) o[nt] = f32x4_zero();
  o5 = f32x4_zero();

  // prologue: stage tile t0 into buf 0
  const __bf16* kq = Kh + (size_t)t0 * 64 * HD;
  const __bf16* vq = Vh + t0 * 64;
  {
    char* Kd = (char*)&KVl[0][0][0] + ldsoff;
    char* Vd = (char*)&KVl[0][1][0] + ldsoff;
    async16(kq + kL0, Kd);
    async16(kq + kL1, Kd + 4096);
    async16(vq + vL0, Vd);
    async16(vq + vL1, Vd + 4096);
    __syncthreads();
  }
  kq += (size_t)64 * HD;
  vq += 64;

  int cur = 0;
  for (int i = t0; i < t1; ++i) {
    const bool more = (i + 1) < t1;
    if (more) {  // DMA next tile into buf^1 (drained by end-of-iter barrier)
      char* Kd = (char*)&KVl[cur ^ 1][0][0] + ldsoff;
      char* Vd = (char*)&KVl[cur ^ 1][1][0] + ldsoff;
      async16(kq + kL0, Kd);
      async16(kq + kL1, Kd + 4096);
      async16(vq + vL0, Vd);
      async16(vq + vL1, Vd + 4096);
      kq += (size_t)64 * HD;
      vq += 64;
    }

    const __bf16* Kl = &KVl[cur][0][0];
    const __bf16* Vl = &KVl[cur][1][0];
    const bool diag = hasDiag && (i == c);

    // ---- QK^T + fused softmax -> P bounce ----
    if (!diag) {
#pragma unroll
      for (int jt = 0; jt < 4; ++jt) {
        int row = 16 * jt + ln;
        bf16x8 kf0 = *(const bf16x8*)(Kl + row * 64 + ((g ^ (row & 7)) << 3));
        bf16x8 kf1 = *(const bf16x8*)(Kl + row * 64 + (((4 + g) ^ (row & 7)) << 3));
        f32x4 z = f32x4_zero();
        z = __builtin_amdgcn_mfma_f32_16x16x32_bf16(kf0, qf[0], z, 0, 0, 0);
        z = __builtin_amdgcn_mfma_f32_16x16x32_bf16(kf1, qf[1], z, 0, 0, 0);
        bf16x4 qd;
#pragma unroll
        for (int r = 0; r < 4; ++r) qd[r] = (__bf16)__builtin_exp2f(z[r]);
        *(bf16x4*)(Pw + ((32 * jt + 8 * g) ^ sw)) = qd;
      }
    } else {
#pragma unroll
      for (int jt = 0; jt < 4; ++jt) {
        int row = 16 * jt + ln;
        bf16x8 kf0 = *(const bf16x8*)(Kl + row * 64 + ((g ^ (row & 7)) << 3));
        bf16x8 kf1 = *(const bf16x8*)(Kl + row * 64 + (((4 + g) ^ (row & 7)) << 3));
        f32x4 z = f32x4_zero();
        z = __builtin_amdgcn_mfma_f32_16x16x32_bf16(kf0, qf[0], z, 0, 0, 0);
        z = __builtin_amdgcn_mfma_f32_16x16x32_bf16(kf1, qf[1], z, 0, 0, 0);
        bf16x4 qd;
#pragma unroll
        for (int r = 0; r < 4; ++r) {
          float pv = __builtin_exp2f(z[r]);
          if (16 * jt + 4 * g + r > thr) pv = 0.f;
          qd[r] = (__bf16)pv;
        }
        *(bf16x4*)(Pw + ((32 * jt + 8 * g) ^ sw)) = qd;
      }
    }

    // ---- PV + ones row-sum ----
    bf16x8 pa0 = *(const bf16x8*)(Pw + ((16 * g) ^ sw));
    bf16x8 pa1 = *(const bf16x8*)(Pw + ((64 + 16 * g) ^ sw));
    __builtin_amdgcn_s_setprio(1);
    o5 = __builtin_amdgcn_mfma_f32_16x16x32_bf16(pa0, ones, o5, 0, 0, 0);
    o5 = __builtin_amdgcn_mfma_f32_16x16x32_bf16(pa1, ones, o5, 0, 0, 0);
#pragma unroll
    for (int nt = 0; nt < 4; ++nt) {
      int row = 16 * nt + ln;
      bf16x8 vf0 = *(const bf16x8*)(Vl + row * 64 + ((g ^ (row & 7)) << 3));
      bf16x8 vf1 = *(const bf16x8*)(Vl + row * 64 + (((4 + g) ^ (row & 7)) << 3));
      o[nt] = __builtin_amdgcn_mfma_f32_16x16x32_bf16(pa0, vf0, o[nt], 0, 0, 0);
      o[nt] = __builtin_amdgcn_mfma_f32_16x16x32_bf16(pa1, vf1, o[nt], 0, 0, 0);
    }
    __builtin_amdgcn_s_setprio(0);

    if (more) __syncthreads();  // drains DMA (vmcnt0) + publishes buf^1
    cur ^= 1;
  }

  if (!split) {
    // direct write Y: lane holds O[q=4g+r][d=16nt+ln]
    const int bb = head / NH, hh = head - bb * NH;
    __bf16* Yp = Y + ((size_t)bb * S_LEN) * DMODEL + hh * HD;
#pragma unroll
    for (int r = 0; r < 4; ++r) {
      float inv = 1.0f / o5[r];
      int qr = q0 + 4 * g + r;
#pragma unroll
      for (int nt = 0; nt < 4; ++nt)
        Yp[(size_t)qr * DMODEL + 16 * nt + ln] = (__bf16)(o[nt][r] * inv);
    }
  } else {
    // partial slab: O bf16 [64 rows][64 d] + rowsum f32 [64]
    char* slab = Po + (size_t)(((head << 5) + (c - 32)) * 2 + part) * SLAB_STRIDE;
#pragma unroll
    for (int r = 0; r < 4; ++r) {
      int rowL = 16 * wv + 4 * g + r;
#pragma unroll
      for (int nt = 0; nt < 4; ++nt)
        *(__bf16*)(slab + (rowL * 64 + 16 * nt + ln) * 2) = (__bf16)o[nt][r];
      if (ln == 0) *(float*)(slab + 8192 + rowL * 4) = o5[r];
    }
  }
}

// ---------------- combine split-chunk partials (64-row chunks, 32 rows/block) ----------------
__global__ __launch_bounds__(256) void attn_combine(const char* __restrict__ Po,
                                                    __bf16* __restrict__ Y) {
  const int blk = blockIdx.x;  // 0..1535 = (head, chunk-32, half)
  const int head = blk >> 6, rem = blk & 63;
  const int cc = rem >> 1, half = rem & 1;
  const int c = cc + 32;
  const char* s0 = Po + (size_t)(((head << 5) + cc) * 2) * SLAB_STRIDE;
  const char* s1 = s0 + SLAB_STRIDE;
  const int tid = threadIdx.x;
  const int row = half * 32 + (tid >> 3), d0 = (tid & 7) * 8;

  bf16x8 a = *(const bf16x8*)(s0 + (row * 64 + d0) * 2);
  bf16x8 b = *(const bf16x8*)(s1 + (row * 64 + d0) * 2);
  float rs = *(const float*)(s0 + 8192 + row * 4) + *(const float*)(s1 + 8192 + row * 4);
  float inv = 1.0f / rs;

  const int bb = head / NH, hh = head - bb * NH;
  __bf16* yp = Y + ((size_t)bb * S_LEN + 64 * c + row) * DMODEL + hh * HD + d0;
  bf16x8 o;
#pragma unroll
  for (int j = 0; j < 8; ++j) o[j] = (__bf16)(((float)a[j] + (float)b[j]) * inv);
  *(bf16x8*)yp = o;
}

extern "C" void kernel_launch(void* const* d_in, const int* in_sizes, int n_in,
                              void* d_out, int out_size, void* d_ws, size_t ws_size,
                              hipStream_t stream) {
  const float* x = (const float*)d_in[0];
  const float* Wqkv = (const float*)d_in[1];
  const float* bqkv = (const float*)d_in[2];
  const float* Wout = (const float*)d_in[3];
  const float* bout = (const float*)d_in[4];
  float* out = (float*)d_out;

  char* ws = (char*)d_ws;
  size_t off = 0;
  auto take = [&](size_t bytes) {
    char* p = ws + off;
    off += bytes;
    return p;
  };
  const size_t MD2 = (size_t)MTOT * DMODEL * 2;
  __bf16* xb = (__bf16*)take(MD2);
  __bf16* Wqkv_t = (__bf16*)take((size_t)3 * DMODEL * DMODEL * 2);
  __bf16* Wout_t = (__bf16*)take((size_t)DMODEL * DMODEL * 2);
  __bf16* Qb = (__bf16*)take(MD2);
  __bf16* Kb = (__bf16*)take(MD2);
  __bf16* Vtb = (__bf16*)take(MD2);
  __bf16* Yb = (__bf16*)take(MD2);
  char* Po = take((size_t)1536 * SLAB_STRIDE);  // 24 heads x 32 split chunks x 2 parts

  int n8 = MTOT * DMODEL / 8;
  cvt_f32_bf16<<<(n8 + 255) / 256, 256, 0, stream>>>(x, xb, n8);
  transpose_cvt<<<dim3(DMODEL / 64, 3 * DMODEL / 64), 256, 0, stream>>>(Wqkv, Wqkv_t, 3 * DMODEL);
  transpose_cvt<<<dim3(DMODEL / 64, DMODEL / 64), 256, 0, stream>>>(Wout, Wout_t, DMODEL);
  gemm_qkv<<<64 * (3 * DMODEL / 128), 256, 0, stream>>>(xb, Wqkv_t, bqkv, Qb, Kb, Vtb);
  attn_fwd14<<<2304, 256, 0, stream>>>(Qb, Kb, Vtb, Yb, Po);
  attn_combine<<<1536, 256, 0, stream>>>(Po, Yb);
  gemm_out<<<64 * (DMODEL / 128), 256, 0, stream>>>(Yb, Wout_t, bout, out);
}